// Round 4
// baseline (149.096 us; speedup 1.0000x reference)
//
#include <hip/hip_runtime.h>
#include <hip/hip_bf16.h>
#include <cmath>

#define B_     8
#define C_     512
#define N_     1024
#define HEADS_ 8
#define HD_    64
#define INST_  64   // B_ * HEADS_

typedef short     v8s __attribute__((ext_vector_type(8)));
typedef _Float16  v8h __attribute__((ext_vector_type(8)));
typedef float    v16f __attribute__((ext_vector_type(16)));
typedef unsigned short ushort_t;
typedef unsigned int   uint_t;

__device__ inline ushort_t f2h(float x) {
    _Float16 h = (_Float16)x;
    ushort_t r; __builtin_memcpy(&r, &h, 2); return r;
}
// packed f32x2 -> bf16x2 (v_cvt_pk_bf16_f32); low short = .x
__device__ inline uint_t pkbf(float a, float b) {
    __hip_bfloat162 p = __float22bfloat162_rn(make_float2(a, b));
    uint_t r; __builtin_memcpy(&r, &p, 4); return r;
}

// ---------------------------------------------------------------------------
// Kernel 0: weights-only transpose + fp16 prep (unchanged from R3).
// ---------------------------------------------------------------------------
__global__ __launch_bounds__(256) void prep_kernel(
    const float* __restrict__ wq, const float* __restrict__ wk,
    const float* __restrict__ wv,
    uint_t* __restrict__ wt)
{
    __shared__ uint_t LH[64 * 32];
    const int z = blockIdx.z;
    const float* src = (z == 0) ? wq : (z == 1) ? wk : wv;
    const size_t outRow0 = (size_t)z * 512 + blockIdx.x * 64;

    const int d0 = blockIdx.x * 64;
    const int c0 = blockIdx.y * 64;
    const int t  = threadIdx.x;

    #pragma unroll
    for (int rep = 0; rep < 2; ++rep) {
        int idx = rep * 256 + t;
        int cp  = idx >> 4;
        int dq  = idx & 15;
        float4 fa = *(const float4*)&src[(size_t)(c0 + 2 * cp) * 512 + d0 + dq * 4];
        float4 fb = *(const float4*)&src[(size_t)(c0 + 2 * cp + 1) * 512 + d0 + dq * 4];
        float aa[4] = {fa.x, fa.y, fa.z, fa.w};
        float bb[4] = {fb.x, fb.y, fb.z, fb.w};
        #pragma unroll
        for (int j = 0; j < 4; ++j) {
            int d_l = dq * 4 + j;
            LH[d_l * 32 + (cp ^ (d_l & 31))] =
                (uint_t)f2h(aa[j]) | ((uint_t)f2h(bb[j]) << 16);
        }
    }
    __syncthreads();

    const int d_l = t >> 2;
    const int wq4 = (t & 3) * 8;
    uint_t vh[8];
    #pragma unroll
    for (int i = 0; i < 8; ++i)
        vh[i] = LH[d_l * 32 + ((wq4 + i) ^ (d_l & 31))];
    size_t base = (outRow0 + d_l) * 256 + c0 / 2 + wq4;
    *(uint4*)&((uint_t*)wt)[base]     = *(uint4*)&vh[0];
    *(uint4*)&((uint_t*)wt)[base + 4] = *(uint4*)&vh[4];
}

// ---------------------------------------------------------------------------
// Kernel 1: MFMA QKV projection, fp16. NEW this round:
//  - tile 128 tok x 128 d (grid 64x12 = 768 blocks, 3/CU); each wave 64x64
//    out (acc 2x2xv16f) -> 8 MFMA per wave-step vs 4, at 8 ds_read_b128.
//  - conflict-free fragment reads: row swizzle s(r) = (r&3)^((r>>2)&3)
//    (old &3-only left rows r, r+4, r+8.. in the same 4-bank window -> 2x
//    serialization on every af/bf read; the 8M conflict cycles of R3).
//  - double-buffered LDS (2 x 16 KB), one barrier per K-step.
//  - A staged directly from x (fused fp32->fp16 transpose, as R3).
// ---------------------------------------------------------------------------
__global__ __launch_bounds__(256, 3) void proj_kernel(
    const float* __restrict__ x, const _Float16* __restrict__ wt,
    const float* __restrict__ bq, const float* __restrict__ bk,
    const float* __restrict__ bv,
    ushort_t* __restrict__ qf, ushort_t* __restrict__ kf,
    ushort_t* __restrict__ vt)
{
    // 32 KB: 2 buffers x (As 4096 halfs + Bs 4096 halfs).
    // V-epilogue reuses all 32 KB as 4 x 8 KB wave-private TW after sync.
    __shared__ _Float16 POOL[16384];

    const int tok0  = blockIdx.x * 128;
    const int b     = tok0 >> 10;
    const int ntb   = tok0 & 1023;
    const int by    = blockIdx.y;
    const int which = by >> 2;                       // 0=q,1=k,2=v
    const int nloc0 = (by & 3) * 128;

    const int t   = threadIdx.x;
    const int w   = t >> 6;
    const int l   = t & 63;
    const int l31 = l & 31;
    const int h5  = l >> 5;
    const int wm  = w & 1;                           // tok half (64 each)
    const int wn  = w >> 1;                          // d half (64 each)

    // B staging mapping: thread covers half-row g of row r0 (+ row 64+r0)
    const int g   = t & 3;
    const int r0  = t >> 2;                          // 0..63
    const int sr0 = (r0 & 3) ^ ((r0 >> 2) & 3);      // new swizzle
    const _Float16* baseB = wt + (size_t)(which * 512 + nloc0 + r0) * 512 + g * 8;

    // A staging mapping: thread = channel pair {2cp,2cp+1} x toks [8tq,8tq+8)
    const int cp = t & 15;
    const int tq = t >> 4;                           // 0..15
    const float* baseX = x + (size_t)b * 524288 + (size_t)(2 * cp) * 1024
                       + ntb + 8 * tq;

    float4 pa00, pa01, pa10, pa11; v8h pfb0, pfb1;   // static names -> VGPRs
    auto load_tile = [&](int s) {
        const float* px = baseX + (size_t)s * 32768;
        pa00 = *(const float4*)(px);
        pa01 = *(const float4*)(px + 4);
        pa10 = *(const float4*)(px + 1024);
        pa11 = *(const float4*)(px + 1028);
        pfb0 = *(const v8h*)(baseB + s * 32);
        pfb1 = *(const v8h*)(baseB + 32768 + s * 32);    // +64 rows
    };
    auto store_tile = [&](int off) {
        uint_t* Asu = (uint_t*)(POOL + off);
        float a0[8] = {pa00.x, pa00.y, pa00.z, pa00.w,
                       pa01.x, pa01.y, pa01.z, pa01.w};
        float a1[8] = {pa10.x, pa10.y, pa10.z, pa10.w,
                       pa11.x, pa11.y, pa11.z, pa11.w};
        #pragma unroll
        for (int i = 0; i < 8; ++i) {                // static index i (rule #20)
            int rm  = 8 * tq + i;
            int srm = (rm & 3) ^ ((rm >> 2) & 3);
            Asu[rm * 16 + ((cp >> 2) ^ srm) * 4 + (cp & 3)] =
                (uint_t)f2h(a0[i]) | ((uint_t)f2h(a1[i]) << 16);
        }
        _Float16* Bs = POOL + off + 4096;
        *(v8h*)&Bs[(r0 * 4 + (g ^ sr0)) * 8] = pfb0;
        // s(64+r0) == s(r0)
        *(v8h*)&Bs[((64 + r0) * 4 + (g ^ sr0)) * 8] = pfb1;
    };

    v16f acc[2][2] = {{{}, {}}, {{}, {}}};           // [mi][ni] 64 tok x 64 d

    load_tile(0);
    store_tile(0);
    __syncthreads();

    for (int step = 0; step < 16; ++step) {
        const int off  = (step & 1) ? 8192 : 0;      // compute buffer
        const int offn = (step & 1) ? 0 : 8192;      // prefetch target
        if (step < 15) load_tile(step + 1);          // in flight during compute

        #pragma unroll
        for (int kc = 0; kc < 2; ++kc) {
            v8h af[2], bf[2];
            #pragma unroll
            for (int mi = 0; mi < 2; ++mi) {
                int rm  = wm * 64 + mi * 32 + l31;
                int srm = (rm & 3) ^ ((rm >> 2) & 3);
                af[mi] = *(const v8h*)&POOL[off +
                           (rm * 4 + ((kc * 2 + h5) ^ srm)) * 8];
            }
            #pragma unroll
            for (int ni = 0; ni < 2; ++ni) {
                int rn  = wn * 64 + ni * 32 + l31;
                int srn = (rn & 3) ^ ((rn >> 2) & 3);
                bf[ni] = *(const v8h*)&POOL[off + 4096 +
                           (rn * 4 + ((kc * 2 + h5) ^ srn)) * 8];
            }
            #pragma unroll
            for (int mi = 0; mi < 2; ++mi)
                #pragma unroll
                for (int ni = 0; ni < 2; ++ni)
                    acc[mi][ni] = __builtin_amdgcn_mfma_f32_32x32x16_f16(
                        af[mi], bf[ni], acc[mi][ni], 0, 0, 0);
        }

        if (step < 15) {
            store_tile(offn);                 // vmcnt wait here, post-compute
            __syncthreads();                  // publishes writes + retires reads
        }
    }

    // ---- epilogue ----
    if (which < 2) {
        ushort_t* oh = (which == 0) ? qf : kf;
        const float* bias = (which == 0) ? bq : bk;
        #pragma unroll
        for (int ni = 0; ni < 2; ++ni) {
            int d_local = nloc0 + wn * 64 + ni * 32 + l31;
            float bvv  = bias[d_local];
            int head   = d_local >> 6;
            int hd     = d_local & 63;
            size_t pb  = (size_t)(b * HEADS_ + head) * 65536 + hd;
            #pragma unroll
            for (int mi = 0; mi < 2; ++mi)
                #pragma unroll
                for (int r = 0; r < 16; ++r) {
                    int n = ntb + wm * 64 + mi * 32
                          + (r & 3) + 8 * (r >> 2) + 4 * h5;
                    oh[pb + (size_t)n * 64] = f2h(acc[mi][ni][r] + bvv);
                }
        }
    } else {
        float bvv[2];
        #pragma unroll
        for (int ni = 0; ni < 2; ++ni)
            bvv[ni] = bv[nloc0 + wn * 64 + ni * 32 + l31];
        __syncthreads();                 // staging LDS fully consumed
        uint_t* TW = (uint_t*)POOL + w * 2048;   // wave-private 8 KB: [64 hd][32 w]
        #pragma unroll
        for (int mi = 0; mi < 2; ++mi)
            #pragma unroll
            for (int ni = 0; ni < 2; ++ni)
                #pragma unroll
                for (int r = 0; r < 16; r += 2) {
                    int tok_l = mi * 32 + (r & 3) + 8 * (r >> 2) + 4 * h5; // even
                    int hd_l  = ni * 32 + l31;
                    TW[hd_l * 32 + ((tok_l >> 1) ^ (hd_l & 31))] =
                        pkbf(acc[mi][ni][r] + bvv[ni],
                             acc[mi][ni][r + 1] + bvv[ni]);
                }
        __syncthreads();
        const int head = (nloc0 + wn * 64) >> 6;
        uint_t* vtu = (uint_t*)vt;
        size_t base = (size_t)(b * HEADS_ + head) * 32768 + (size_t)l * 512
                    + (ntb + wm * 64) / 2;
        // kv-permutation baked into column order: swap bits 1<->2 of word idx
        // within each 8-word (16-token) block.
        #pragma unroll
        for (int c = 0; c < 8; ++c) {
            uint_t wd[4];
            #pragma unroll
            for (int kk = 0; kk < 4; ++kk) {
                int wsx = c * 4 + kk;
                int w3 = wsx & 7;
                int sw = (wsx & ~7) | (w3 & 1) | (((w3 >> 1) & 1) << 2)
                                   | (((w3 >> 2) & 1) << 1);
                wd[kk] = TW[l * 32 + (sw ^ (l & 31))];
            }
            *(uint4*)&vtu[base + c * 4] = *(uint4*)&wd[0];
        }
    }
}

// ---------------------------------------------------------------------------
// Kernel 2: MFMA flash attention, S^T form, fp16 QK^T + bf16 PV.
// Exact R0 structure (setprio reverted: our 4-wave lockstep block is the
// m190-null regime, and R3 regressed with it in).
// ---------------------------------------------------------------------------
__global__ __launch_bounds__(256) void attn_kernel(
    const ushort_t* __restrict__ qf, const ushort_t* __restrict__ kf,
    const ushort_t* __restrict__ vt, float* __restrict__ out)
{
    __shared__ _Float16 KH[4096];      // K tile [kv][d] fp16, swizzled
    __shared__ ushort_t VT[4096];      // V^T tile [hd][kv-perm] bf16
    __shared__ float    RS[128];

    const int inst  = blockIdx.x;
    const int chunk = blockIdx.y;
    const int t     = threadIdx.x;
    const int w     = t >> 6;
    const int l     = t & 63;
    const int l31   = l & 31;
    const int h5    = l >> 5;

    const ushort_t* Qf = qf + (size_t)inst * 65536;
    const ushort_t* Kf = kf + (size_t)inst * 65536;
    const ushort_t* Vt = vt + (size_t)inst * 65536;

    const int qbase = chunk * 128 + w * 32;

    v8h aq[4];
    #pragma unroll
    for (int ks = 0; ks < 4; ++ks)
        aq[ks] = *(const v8h*)&Qf[(size_t)(qbase + l31) * 64 + ks * 16 + h5 * 8];

    const int g   = t & 7;
    const int r0  = t >> 3;            // 0..31, rep adds 32
    const int swz = g ^ (r0 & 7);
    const ushort_t* baseK = Kf + (size_t)r0 * 64 + g * 8;
    const ushort_t* baseV = Vt + (size_t)r0 * 1024 + g * 8;

    v8h pk0, pk1; v8s pv0, pv1;        // static names -> VGPRs
    auto load_tile = [&](int kt) {
        pk0 = *(const v8h*)(baseK + (size_t)kt * 4096);
        pk1 = *(const v8h*)(baseK + (size_t)kt * 4096 + 2048);
        pv0 = *(const v8s*)(baseV + (size_t)kt * 64);
        pv1 = *(const v8s*)(baseV + 32768 + (size_t)kt * 64);
    };
    auto store_tile = [&]() {
        int so0 = (r0 * 8 + swz) * 8;
        int so1 = ((32 + r0) * 8 + swz) * 8;
        *(v8h*)&KH[so0] = pk0;
        *(v8h*)&KH[so1] = pk1;
        *(v8s*)&VT[so0] = pv0;
        *(v8s*)&VT[so1] = pv1;
    };

    v16f O0 = {}, O1 = {};
    float rsumv = 0.f;

    load_tile(0);
    store_tile();
    __syncthreads();

    for (int kt = 0; kt < 16; ++kt) {
        if (kt < 15) load_tile(kt + 1);

        #pragma unroll
        for (int t2 = 0; t2 < 2; ++t2) {
            v16f s = {};
            int kvrow = t2 * 32 + l31;
            #pragma unroll
            for (int ks = 0; ks < 4; ++ks) {
                int so = (kvrow * 8 + ((ks * 2 + h5) ^ (kvrow & 7))) * 8;
                v8h khf = *(const v8h*)&KH[so];
                s = __builtin_amdgcn_mfma_f32_32x32x16_f16(khf, aq[ks], s, 0, 0, 0);
            }
            float e0[8], e1[8];
            #pragma unroll
            for (int j = 0; j < 8; ++j) {
                e0[j] = __expf(s[j] - 64.0f);
                e1[j] = __expf(s[8 + j] - 64.0f);
                rsumv += e0[j] + e1[j];
            }
            uint4 u0, u1;
            u0.x = pkbf(e0[0], e0[1]); u0.y = pkbf(e0[2], e0[3]);
            u0.z = pkbf(e0[4], e0[5]); u0.w = pkbf(e0[6], e0[7]);
            u1.x = pkbf(e1[0], e1[1]); u1.y = pkbf(e1[2], e1[3]);
            u1.z = pkbf(e1[4], e1[5]); u1.w = pkbf(e1[6], e1[7]);
            v8s p0 = __builtin_bit_cast(v8s, u0);
            v8s p1 = __builtin_bit_cast(v8s, u1);

            #pragma unroll
            for (int hh = 0; hh < 2; ++hh) {
                int rv = hh * 32 + l31;
                int g0 = (4 * t2 + h5)     ^ (rv & 7);
                int g1 = (4 * t2 + 2 + h5) ^ (rv & 7);
                v8s bv0 = *(const v8s*)&VT[(rv * 8 + g0) * 8];
                v8s bv1 = *(const v8s*)&VT[(rv * 8 + g1) * 8];
                if (hh == 0) {
                    O0 = __builtin_amdgcn_mfma_f32_32x32x16_bf16(p0, bv0, O0, 0, 0, 0);
                    O0 = __builtin_amdgcn_mfma_f32_32x32x16_bf16(p1, bv1, O0, 0, 0, 0);
                } else {
                    O1 = __builtin_amdgcn_mfma_f32_32x32x16_bf16(p0, bv0, O1, 0, 0, 0);
                    O1 = __builtin_amdgcn_mfma_f32_32x32x16_bf16(p1, bv1, O1, 0, 0, 0);
                }
            }
        }

        __syncthreads();
        if (kt < 15) {
            store_tile();
            __syncthreads();
        }
    }

    float tot = rsumv + __shfl_xor(rsumv, 32, 64);
    if (h5 == 0) RS[w * 32 + l31] = 1.0f / tot;
    __syncthreads();
    float invr[16];
    #pragma unroll
    for (int r = 0; r < 16; ++r)
        invr[r] = RS[w * 32 + (r & 3) + 8 * (r >> 2) + 4 * h5];

    const int b    = inst >> 3;
    const int head = inst & 7;
    float* ob = out + (size_t)b * C_ * N_;
    #pragma unroll
    for (int hh = 0; hh < 2; ++hh) {
        const v16f& O = hh ? O1 : O0;
        int c = head * 64 + hh * 32 + l31;
        #pragma unroll
        for (int qd = 0; qd < 4; ++qd) {
            int n = qbase + 8 * qd + 4 * h5;
            float4 o4;
            o4.x = O[qd * 4 + 0] * invr[qd * 4 + 0];
            o4.y = O[qd * 4 + 1] * invr[qd * 4 + 1];
            o4.z = O[qd * 4 + 2] * invr[qd * 4 + 2];
            o4.w = O[qd * 4 + 3] * invr[qd * 4 + 3];
            *(float4*)&ob[(size_t)c * N_ + n] = o4;
        }
    }
}

// ---------------------------------------------------------------------------
extern "C" void kernel_launch(void* const* d_in, const int* in_sizes, int n_in,
                              void* d_out, int out_size, void* d_ws, size_t ws_size,
                              hipStream_t stream) {
    const float* x  = (const float*)d_in[0];
    const float* wq = (const float*)d_in[1];
    const float* bq = (const float*)d_in[2];
    const float* wk = (const float*)d_in[3];
    const float* bk = (const float*)d_in[4];
    const float* wv = (const float*)d_in[5];
    const float* bv = (const float*)d_in[6];
    float* out = (float*)d_out;

    char* ws = (char*)d_ws;                        // ~35 MiB used
    _Float16* wt = (_Float16*)(ws);                // 1536x512 fp16 = 1.5 MiB
    ushort_t* qf = (ushort_t*)(ws + 9961472);      // 8 MiB fp16
    ushort_t* kf = (ushort_t*)(ws + 18350080);     // 8 MiB fp16
    ushort_t* vt = (ushort_t*)(ws + 26738688);     // 8 MiB bf16

    prep_kernel<<<dim3(8, 8, 3), 256, 0, stream>>>(wq, wk, wv, (uint_t*)wt);
    proj_kernel<<<dim3(64, 12), 256, 0, stream>>>(x, wt, bq, bk, bv,
                                                  qf, kf, vt);
    attn_kernel<<<dim3(64, 8), 256, 0, stream>>>(qf, kf, vt, out);
}

// Round 5
// 141.517 us; speedup vs baseline: 1.0536x; 1.0536x over previous
//
#include <hip/hip_runtime.h>
#include <hip/hip_bf16.h>
#include <cmath>

#define B_     8
#define C_     512
#define N_     1024
#define HEADS_ 8
#define HD_    64
#define INST_  64   // B_ * HEADS_

typedef short     v8s __attribute__((ext_vector_type(8)));
typedef _Float16  v8h __attribute__((ext_vector_type(8)));
typedef float    v16f __attribute__((ext_vector_type(16)));
typedef unsigned short ushort_t;
typedef unsigned int   uint_t;

__device__ inline ushort_t f2h(float x) {
    _Float16 h = (_Float16)x;
    ushort_t r; __builtin_memcpy(&r, &h, 2); return r;
}
// packed f32x2 -> bf16x2 (v_cvt_pk_bf16_f32); low short = .x
__device__ inline uint_t pkbf(float a, float b) {
    __hip_bfloat162 p = __float22bfloat162_rn(make_float2(a, b));
    uint_t r; __builtin_memcpy(&r, &p, 4); return r;
}

// ---------------------------------------------------------------------------
// Kernel 0: weights-only transpose + fp16 prep (unchanged).
// ---------------------------------------------------------------------------
__global__ __launch_bounds__(256) void prep_kernel(
    const float* __restrict__ wq, const float* __restrict__ wk,
    const float* __restrict__ wv,
    uint_t* __restrict__ wt)
{
    __shared__ uint_t LH[64 * 32];
    const int z = blockIdx.z;
    const float* src = (z == 0) ? wq : (z == 1) ? wk : wv;
    const size_t outRow0 = (size_t)z * 512 + blockIdx.x * 64;

    const int d0 = blockIdx.x * 64;
    const int c0 = blockIdx.y * 64;
    const int t  = threadIdx.x;

    #pragma unroll
    for (int rep = 0; rep < 2; ++rep) {
        int idx = rep * 256 + t;
        int cp  = idx >> 4;
        int dq  = idx & 15;
        float4 fa = *(const float4*)&src[(size_t)(c0 + 2 * cp) * 512 + d0 + dq * 4];
        float4 fb = *(const float4*)&src[(size_t)(c0 + 2 * cp + 1) * 512 + d0 + dq * 4];
        float aa[4] = {fa.x, fa.y, fa.z, fa.w};
        float bb[4] = {fb.x, fb.y, fb.z, fb.w};
        #pragma unroll
        for (int j = 0; j < 4; ++j) {
            int d_l = dq * 4 + j;
            LH[d_l * 32 + (cp ^ (d_l & 31))] =
                (uint_t)f2h(aa[j]) | ((uint_t)f2h(bb[j]) << 16);
        }
    }
    __syncthreads();

    const int d_l = t >> 2;
    const int wq4 = (t & 3) * 8;
    uint_t vh[8];
    #pragma unroll
    for (int i = 0; i < 8; ++i)
        vh[i] = LH[d_l * 32 + ((wq4 + i) ^ (d_l & 31))];
    size_t base = (outRow0 + d_l) * 256 + c0 / 2 + wq4;
    *(uint4*)&((uint_t*)wt)[base]     = *(uint4*)&vh[0];
    *(uint4*)&((uint_t*)wt)[base + 4] = *(uint4*)&vh[4];
}

// ---------------------------------------------------------------------------
// Kernel 1: MFMA QKV projection, fp16. R5: back to the 64 tok x 128 d tile
// (1536 blocks, ~6/CU TLP) with R4's conflict-free swizzle, PLUS 2-deep
// register prefetch over double-buffered LDS: at step s we issue loads for
// tile s+2 (set just freed), compute tile s from LDS, then store tile s+1's
// registers (loaded one full step ago -> compiler waits vmcnt(4), the 4
// newer loads stay in flight across the barrier; never drains to 0).
// ---------------------------------------------------------------------------
__global__ __launch_bounds__(256) void proj_kernel(
    const float* __restrict__ x, const _Float16* __restrict__ wt,
    const float* __restrict__ bq, const float* __restrict__ bk,
    const float* __restrict__ bv,
    ushort_t* __restrict__ qf, ushort_t* __restrict__ kf,
    ushort_t* __restrict__ vt)
{
    // 24 KB: 2 buffers x (As 2048 + Bs 4096 halfs). V-epi reuses 16 KB.
    __shared__ _Float16 POOL[12288];

    const int tok0  = blockIdx.x * 64;
    const int b     = tok0 >> 10;
    const int ntb   = tok0 & 1023;
    const int by    = blockIdx.y;
    const int which = by >> 2;                       // 0=q,1=k,2=v
    const int nloc0 = (by & 3) * 128;

    const int t   = threadIdx.x;
    const int w   = t >> 6;
    const int l   = t & 63;
    const int l31 = l & 31;
    const int h5  = l >> 5;
    const int wm  = w & 1;                           // tok half (32 each)
    const int wn  = w >> 1;                          // d half (64 each)

    // B staging mapping
    const int g   = t & 3;
    const int r0  = t >> 2;                          // 0..63
    const int sr0 = (r0 & 3) ^ ((r0 >> 2) & 3);      // conflict-free swizzle
    const _Float16* baseB = wt + (size_t)(which * 512 + nloc0 + r0) * 512 + g * 8;

    // A staging: thread = channel pair {2cp,2cp+1} x toks [4tq, 4tq+4)
    const int cp = t & 15;
    const int tq = t >> 4;                           // 0..15
    const float* baseX = x + (size_t)b * 524288 + (size_t)(2 * cp) * 1024
                       + ntb + 4 * tq;

    // two static-named prefetch sets (rule #20: no runtime-indexed regs)
    float4 paE0, paE1, paO0, paO1;
    v8h    pbE0, pbE1, pbO0, pbO1;

    auto loadE = [&](int s) {
        const float* px = baseX + (size_t)s * 32768;
        paE0 = *(const float4*)(px);
        paE1 = *(const float4*)(px + 1024);
        pbE0 = *(const v8h*)(baseB + s * 32);
        pbE1 = *(const v8h*)(baseB + 32768 + s * 32);
    };
    auto loadO = [&](int s) {
        const float* px = baseX + (size_t)s * 32768;
        paO0 = *(const float4*)(px);
        paO1 = *(const float4*)(px + 1024);
        pbO0 = *(const v8h*)(baseB + s * 32);
        pbO1 = *(const v8h*)(baseB + 32768 + s * 32);
    };
    auto storeE = [&](int off) {
        uint_t* Asu = (uint_t*)(POOL + off);
        float a0[4] = {paE0.x, paE0.y, paE0.z, paE0.w};
        float a1[4] = {paE1.x, paE1.y, paE1.z, paE1.w};
        #pragma unroll
        for (int i = 0; i < 4; ++i) {
            int rm  = 4 * tq + i;
            int srm = i ^ (tq & 3);
            Asu[rm * 16 + ((cp >> 2) ^ srm) * 4 + (cp & 3)] =
                (uint_t)f2h(a0[i]) | ((uint_t)f2h(a1[i]) << 16);
        }
        _Float16* Bs = POOL + off + 2048;
        *(v8h*)&Bs[(r0 * 4 + (g ^ sr0)) * 8] = pbE0;
        *(v8h*)&Bs[((64 + r0) * 4 + (g ^ sr0)) * 8] = pbE1;   // s(64+r)==s(r)
    };
    auto storeO = [&](int off) {
        uint_t* Asu = (uint_t*)(POOL + off);
        float a0[4] = {paO0.x, paO0.y, paO0.z, paO0.w};
        float a1[4] = {paO1.x, paO1.y, paO1.z, paO1.w};
        #pragma unroll
        for (int i = 0; i < 4; ++i) {
            int rm  = 4 * tq + i;
            int srm = i ^ (tq & 3);
            Asu[rm * 16 + ((cp >> 2) ^ srm) * 4 + (cp & 3)] =
                (uint_t)f2h(a0[i]) | ((uint_t)f2h(a1[i]) << 16);
        }
        _Float16* Bs = POOL + off + 2048;
        *(v8h*)&Bs[(r0 * 4 + (g ^ sr0)) * 8] = pbO0;
        *(v8h*)&Bs[((64 + r0) * 4 + (g ^ sr0)) * 8] = pbO1;
    };

    v16f acc[2] = {{}, {}};            // [ns]: 32 tok x 2x32 d

    auto compute = [&](int off) {
        #pragma unroll
        for (int kc = 0; kc < 2; ++kc) {
            int rm  = wm * 32 + l31;
            int srm = (rm & 3) ^ ((rm >> 2) & 3);
            v8h af = *(const v8h*)&POOL[off + (rm * 4 + ((kc * 2 + h5) ^ srm)) * 8];
            v8h bf[2];
            #pragma unroll
            for (int ns = 0; ns < 2; ++ns) {
                int rn  = wn * 64 + ns * 32 + l31;
                int srn = (rn & 3) ^ ((rn >> 2) & 3);
                bf[ns] = *(const v8h*)&POOL[off + 2048 +
                           (rn * 4 + ((kc * 2 + h5) ^ srn)) * 8];
            }
            #pragma unroll
            for (int ns = 0; ns < 2; ++ns)
                acc[ns] = __builtin_amdgcn_mfma_f32_32x32x16_f16(
                    af, bf[ns], acc[ns], 0, 0, 0);
        }
    };

    // prologue: tile0 -> regsE -> LDS0; tile1 -> regsO (in flight)
    loadE(0);
    loadO(1);
    storeE(0);                 // waits only the 4 E-loads (vmcnt(4))
    __syncthreads();

    for (int sp = 0; sp < 8; ++sp) {
        const int s = 2 * sp;
        // even step: compute tile s from buf0
        if (s < 14) loadE(s + 2);          // into freed E set
        compute(0);
        storeO(6144);                      // tile s+1; loads 1 step old
        __syncthreads();
        // odd step: compute tile s+1 from buf1
        if (s < 13) loadO(s + 3);
        compute(6144);
        if (s < 14) {
            storeE(0);                     // tile s+2
            __syncthreads();
        }
    }

    // ---- epilogue ----
    if (which < 2) {
        ushort_t* oh = (which == 0) ? qf : kf;
        const float* bias = (which == 0) ? bq : bk;
        #pragma unroll
        for (int ns = 0; ns < 2; ++ns) {
            int d_local = nloc0 + wn * 64 + ns * 32 + l31;
            float bvv  = bias[d_local];
            int head   = d_local >> 6;
            int hd     = d_local & 63;
            size_t pb  = (size_t)(b * HEADS_ + head) * 65536 + hd;
            #pragma unroll
            for (int r = 0; r < 16; ++r) {
                int n = ntb + wm * 32 + (r & 3) + 8 * (r >> 2) + 4 * h5;
                oh[pb + (size_t)n * 64] = f2h(acc[ns][r] + bvv);
            }
        }
    } else {
        float bvv[2];
        #pragma unroll
        for (int ns = 0; ns < 2; ++ns)
            bvv[ns] = bv[nloc0 + wn * 64 + ns * 32 + l31];
        __syncthreads();                 // staging LDS fully consumed
        uint_t* TW = (uint_t*)POOL + w * 1024;   // wave-private 4 KB: [64 hd][16 w]
        #pragma unroll
        for (int ns = 0; ns < 2; ++ns)
            #pragma unroll
            for (int r = 0; r < 16; r += 2) {
                int tok_l = (r & 3) + 8 * (r >> 2) + 4 * h5;   // even
                int hd_l  = ns * 32 + l31;
                TW[hd_l * 16 + ((tok_l >> 1) ^ (hd_l & 15))] =
                    pkbf(acc[ns][r] + bvv[ns], acc[ns][r + 1] + bvv[ns]);
            }
        __syncthreads();
        const int head = (nloc0 + wn * 64) >> 6;
        uint_t* vtu = (uint_t*)vt;
        size_t base = (size_t)(b * HEADS_ + head) * 32768 + (size_t)l * 512
                    + (ntb + wm * 32) / 2;
        // kv-permutation baked into column order: swap bits 1<->2 of word idx
        // within each 8-word (16-token) block.
        #pragma unroll
        for (int c = 0; c < 4; ++c) {
            uint_t wd[4];
            #pragma unroll
            for (int kk = 0; kk < 4; ++kk) {
                int wsx = c * 4 + kk;
                int w3 = wsx & 7;
                int sw = (wsx & ~7) | (w3 & 1) | (((w3 >> 1) & 1) << 2)
                                   | (((w3 >> 2) & 1) << 1);
                wd[kk] = TW[l * 16 + (sw ^ (l & 15))];
            }
            *(uint4*)&vtu[base + c * 4] = *(uint4*)&wd[0];
        }
    }
}

// ---------------------------------------------------------------------------
// Kernel 2: MFMA flash attention, S^T form, fp16 QK^T + bf16 PV.
// R5: same 2-deep prefetch over double-buffered KH/VT (one barrier/step,
// vmcnt never drained to 0 in steady state).
// ---------------------------------------------------------------------------
__global__ __launch_bounds__(256) void attn_kernel(
    const ushort_t* __restrict__ qf, const ushort_t* __restrict__ kf,
    const ushort_t* __restrict__ vt, float* __restrict__ out)
{
    __shared__ _Float16 KH[8192];      // 2 x: K tile [kv][d] fp16, swizzled
    __shared__ ushort_t VT[8192];      // 2 x: V^T tile [hd][kv-perm] bf16
    __shared__ float    RS[128];

    const int inst  = blockIdx.x;
    const int chunk = blockIdx.y;
    const int t     = threadIdx.x;
    const int w     = t >> 6;
    const int l     = t & 63;
    const int l31   = l & 31;
    const int h5    = l >> 5;

    const ushort_t* Qf = qf + (size_t)inst * 65536;
    const ushort_t* Kf = kf + (size_t)inst * 65536;
    const ushort_t* Vt = vt + (size_t)inst * 65536;

    const int qbase = chunk * 128 + w * 32;

    v8h aq[4];
    #pragma unroll
    for (int ks = 0; ks < 4; ++ks)
        aq[ks] = *(const v8h*)&Qf[(size_t)(qbase + l31) * 64 + ks * 16 + h5 * 8];

    const int g   = t & 7;
    const int r0  = t >> 3;            // 0..31, rep adds 32
    const int swz = g ^ (r0 & 7);
    const ushort_t* baseK = Kf + (size_t)r0 * 64 + g * 8;
    const ushort_t* baseV = Vt + (size_t)r0 * 1024 + g * 8;

    // two static-named prefetch sets
    v8h pkE0, pkE1, pkO0, pkO1;
    v8s pvE0, pvE1, pvO0, pvO1;

    auto loadE = [&](int kt) {
        pkE0 = *(const v8h*)(baseK + (size_t)kt * 4096);
        pkE1 = *(const v8h*)(baseK + (size_t)kt * 4096 + 2048);
        pvE0 = *(const v8s*)(baseV + (size_t)kt * 64);
        pvE1 = *(const v8s*)(baseV + 32768 + (size_t)kt * 64);
    };
    auto loadO = [&](int kt) {
        pkO0 = *(const v8h*)(baseK + (size_t)kt * 4096);
        pkO1 = *(const v8h*)(baseK + (size_t)kt * 4096 + 2048);
        pvO0 = *(const v8s*)(baseV + (size_t)kt * 64);
        pvO1 = *(const v8s*)(baseV + 32768 + (size_t)kt * 64);
    };
    auto storeE = [&](int off) {
        int so0 = (r0 * 8 + swz) * 8;
        int so1 = ((32 + r0) * 8 + swz) * 8;
        *(v8h*)&KH[off + so0] = pkE0;
        *(v8h*)&KH[off + so1] = pkE1;
        *(v8s*)&VT[off + so0] = pvE0;
        *(v8s*)&VT[off + so1] = pvE1;
    };
    auto storeO = [&](int off) {
        int so0 = (r0 * 8 + swz) * 8;
        int so1 = ((32 + r0) * 8 + swz) * 8;
        *(v8h*)&KH[off + so0] = pkO0;
        *(v8h*)&KH[off + so1] = pkO1;
        *(v8s*)&VT[off + so0] = pvO0;
        *(v8s*)&VT[off + so1] = pvO1;
    };

    v16f O0 = {}, O1 = {};
    float rsumv = 0.f;

    auto compute = [&](int off) {
        #pragma unroll
        for (int t2 = 0; t2 < 2; ++t2) {
            v16f s = {};
            int kvrow = t2 * 32 + l31;
            #pragma unroll
            for (int ks = 0; ks < 4; ++ks) {
                int so = (kvrow * 8 + ((ks * 2 + h5) ^ (kvrow & 7))) * 8;
                v8h khf = *(const v8h*)&KH[off + so];
                s = __builtin_amdgcn_mfma_f32_32x32x16_f16(khf, aq[ks], s, 0, 0, 0);
            }
            float e0[8], e1[8];
            #pragma unroll
            for (int j = 0; j < 8; ++j) {
                e0[j] = __expf(s[j] - 64.0f);
                e1[j] = __expf(s[8 + j] - 64.0f);
                rsumv += e0[j] + e1[j];
            }
            uint4 u0, u1;
            u0.x = pkbf(e0[0], e0[1]); u0.y = pkbf(e0[2], e0[3]);
            u0.z = pkbf(e0[4], e0[5]); u0.w = pkbf(e0[6], e0[7]);
            u1.x = pkbf(e1[0], e1[1]); u1.y = pkbf(e1[2], e1[3]);
            u1.z = pkbf(e1[4], e1[5]); u1.w = pkbf(e1[6], e1[7]);
            v8s p0 = __builtin_bit_cast(v8s, u0);
            v8s p1 = __builtin_bit_cast(v8s, u1);

            #pragma unroll
            for (int hh = 0; hh < 2; ++hh) {
                int rv = hh * 32 + l31;
                int g0 = (4 * t2 + h5)     ^ (rv & 7);
                int g1 = (4 * t2 + 2 + h5) ^ (rv & 7);
                v8s bv0 = *(const v8s*)&VT[off + (rv * 8 + g0) * 8];
                v8s bv1 = *(const v8s*)&VT[off + (rv * 8 + g1) * 8];
                if (hh == 0) {
                    O0 = __builtin_amdgcn_mfma_f32_32x32x16_bf16(p0, bv0, O0, 0, 0, 0);
                    O0 = __builtin_amdgcn_mfma_f32_32x32x16_bf16(p1, bv1, O0, 0, 0, 0);
                } else {
                    O1 = __builtin_amdgcn_mfma_f32_32x32x16_bf16(p0, bv0, O1, 0, 0, 0);
                    O1 = __builtin_amdgcn_mfma_f32_32x32x16_bf16(p1, bv1, O1, 0, 0, 0);
                }
            }
        }
    };

    // prologue
    loadE(0);
    loadO(1);
    storeE(0);
    __syncthreads();

    for (int sp = 0; sp < 8; ++sp) {
        const int kt = 2 * sp;
        if (kt < 14) loadE(kt + 2);
        compute(0);
        storeO(4096);
        __syncthreads();
        if (kt < 13) loadO(kt + 3);
        compute(4096);
        if (kt < 14) {
            storeE(0);
            __syncthreads();
        }
    }

    float tot = rsumv + __shfl_xor(rsumv, 32, 64);
    if (h5 == 0) RS[w * 32 + l31] = 1.0f / tot;
    __syncthreads();
    float invr[16];
    #pragma unroll
    for (int r = 0; r < 16; ++r)
        invr[r] = RS[w * 32 + (r & 3) + 8 * (r >> 2) + 4 * h5];

    const int b    = inst >> 3;
    const int head = inst & 7;
    float* ob = out + (size_t)b * C_ * N_;
    #pragma unroll
    for (int hh = 0; hh < 2; ++hh) {
        const v16f& O = hh ? O1 : O0;
        int c = head * 64 + hh * 32 + l31;
        #pragma unroll
        for (int qd = 0; qd < 4; ++qd) {
            int n = qbase + 8 * qd + 4 * h5;
            float4 o4;
            o4.x = O[qd * 4 + 0] * invr[qd * 4 + 0];
            o4.y = O[qd * 4 + 1] * invr[qd * 4 + 1];
            o4.z = O[qd * 4 + 2] * invr[qd * 4 + 2];
            o4.w = O[qd * 4 + 3] * invr[qd * 4 + 3];
            *(float4*)&ob[(size_t)c * N_ + n] = o4;
        }
    }
}

// ---------------------------------------------------------------------------
extern "C" void kernel_launch(void* const* d_in, const int* in_sizes, int n_in,
                              void* d_out, int out_size, void* d_ws, size_t ws_size,
                              hipStream_t stream) {
    const float* x  = (const float*)d_in[0];
    const float* wq = (const float*)d_in[1];
    const float* bq = (const float*)d_in[2];
    const float* wk = (const float*)d_in[3];
    const float* bk = (const float*)d_in[4];
    const float* wv = (const float*)d_in[5];
    const float* bv = (const float*)d_in[6];
    float* out = (float*)d_out;

    char* ws = (char*)d_ws;                        // ~35 MiB used
    _Float16* wt = (_Float16*)(ws);                // 1536x512 fp16 = 1.5 MiB
    ushort_t* qf = (ushort_t*)(ws + 9961472);      // 8 MiB fp16
    ushort_t* kf = (ushort_t*)(ws + 18350080);     // 8 MiB fp16
    ushort_t* vt = (ushort_t*)(ws + 26738688);     // 8 MiB bf16

    prep_kernel<<<dim3(8, 8, 3), 256, 0, stream>>>(wq, wk, wv, (uint_t*)wt);
    proj_kernel<<<dim3(128, 12), 256, 0, stream>>>(x, wt, bq, bk, bv,
                                                   qf, kf, vt);
    attn_kernel<<<dim3(64, 8), 256, 0, stream>>>(qf, kf, vt, out);
}

// Round 7
// 139.232 us; speedup vs baseline: 1.0708x; 1.0164x over previous
//
#include <hip/hip_runtime.h>
#include <hip/hip_bf16.h>
#include <cmath>

#define B_     8
#define C_     512
#define N_     1024
#define HEADS_ 8
#define HD_    64
#define INST_  64   // B_ * HEADS_

typedef short     v8s __attribute__((ext_vector_type(8)));
typedef _Float16  v8h __attribute__((ext_vector_type(8)));
typedef float    v16f __attribute__((ext_vector_type(16)));
typedef unsigned short ushort_t;
typedef unsigned int   uint_t;

__device__ inline ushort_t f2h(float x) {
    _Float16 h = (_Float16)x;
    ushort_t r; __builtin_memcpy(&r, &h, 2); return r;
}
// packed f32x2 -> bf16x2 (v_cvt_pk_bf16_f32); low short = .x
__device__ inline uint_t pkbf(float a, float b) {
    __hip_bfloat162 p = __float22bfloat162_rn(make_float2(a, b));
    uint_t r; __builtin_memcpy(&r, &p, 4); return r;
}

// ---------------------------------------------------------------------------
// Kernel 0: weights-only transpose + fp16 prep (unchanged).
// ---------------------------------------------------------------------------
__global__ __launch_bounds__(256) void prep_kernel(
    const float* __restrict__ wq, const float* __restrict__ wk,
    const float* __restrict__ wv,
    uint_t* __restrict__ wt)
{
    __shared__ uint_t LH[64 * 32];
    const int z = blockIdx.z;
    const float* src = (z == 0) ? wq : (z == 1) ? wk : wv;
    const size_t outRow0 = (size_t)z * 512 + blockIdx.x * 64;

    const int d0 = blockIdx.x * 64;
    const int c0 = blockIdx.y * 64;
    const int t  = threadIdx.x;

    #pragma unroll
    for (int rep = 0; rep < 2; ++rep) {
        int idx = rep * 256 + t;
        int cp  = idx >> 4;
        int dq  = idx & 15;
        float4 fa = *(const float4*)&src[(size_t)(c0 + 2 * cp) * 512 + d0 + dq * 4];
        float4 fb = *(const float4*)&src[(size_t)(c0 + 2 * cp + 1) * 512 + d0 + dq * 4];
        float aa[4] = {fa.x, fa.y, fa.z, fa.w};
        float bb[4] = {fb.x, fb.y, fb.z, fb.w};
        #pragma unroll
        for (int j = 0; j < 4; ++j) {
            int d_l = dq * 4 + j;
            LH[d_l * 32 + (cp ^ (d_l & 31))] =
                (uint_t)f2h(aa[j]) | ((uint_t)f2h(bb[j]) << 16);
        }
    }
    __syncthreads();

    const int d_l = t >> 2;
    const int wq4 = (t & 3) * 8;
    uint_t vh[8];
    #pragma unroll
    for (int i = 0; i < 8; ++i)
        vh[i] = LH[d_l * 32 + ((wq4 + i) ^ (d_l & 31))];
    size_t base = (outRow0 + d_l) * 256 + c0 / 2 + wq4;
    *(uint4*)&((uint_t*)wt)[base]     = *(uint4*)&vh[0];
    *(uint4*)&((uint_t*)wt)[base + 4] = *(uint4*)&vh[4];
}

// ---------------------------------------------------------------------------
// Kernel 1: MFMA QKV projection, fp16. Main loop = R5 (2-deep register
// prefetch, double-buffered LDS, conflict-free swizzle). NEW: Q/K epilogue
// LDS-transposes (like the V path always did) so global stores are coalesced
// uint4 token-rows (was: 32 scalar 2B stores/thread at 128B lane-stride ->
// 64 txns per wave-store). Same linear indices -> bit-identical output.
// ---------------------------------------------------------------------------
__global__ __launch_bounds__(256) void proj_kernel(
    const float* __restrict__ x, const _Float16* __restrict__ wt,
    const float* __restrict__ bq, const float* __restrict__ bk,
    const float* __restrict__ bv,
    ushort_t* __restrict__ qf, ushort_t* __restrict__ kf,
    ushort_t* __restrict__ vt)
{
    // 24 KB: 2 buffers x (As 2048 + Bs 4096 halfs). Epilogues reuse 16 KB.
    __shared__ _Float16 POOL[12288];

    const int tok0  = blockIdx.x * 64;
    const int b     = tok0 >> 10;
    const int ntb   = tok0 & 1023;
    const int by    = blockIdx.y;
    const int which = by >> 2;                       // 0=q,1=k,2=v
    const int nloc0 = (by & 3) * 128;

    const int t   = threadIdx.x;
    const int w   = t >> 6;
    const int l   = t & 63;
    const int l31 = l & 31;
    const int h5  = l >> 5;
    const int wm  = w & 1;                           // tok half (32 each)
    const int wn  = w >> 1;                          // d half (64 each)

    // B staging mapping
    const int g   = t & 3;
    const int r0  = t >> 2;                          // 0..63
    const int sr0 = (r0 & 3) ^ ((r0 >> 2) & 3);      // conflict-free swizzle
    const _Float16* baseB = wt + (size_t)(which * 512 + nloc0 + r0) * 512 + g * 8;

    // A staging: thread = channel pair {2cp,2cp+1} x toks [4tq, 4tq+4)
    const int cp = t & 15;
    const int tq = t >> 4;                           // 0..15
    const float* baseX = x + (size_t)b * 524288 + (size_t)(2 * cp) * 1024
                       + ntb + 4 * tq;

    // two static-named prefetch sets (rule #20: no runtime-indexed regs)
    float4 paE0, paE1, paO0, paO1;
    v8h    pbE0, pbE1, pbO0, pbO1;

    auto loadE = [&](int s) {
        const float* px = baseX + (size_t)s * 32768;
        paE0 = *(const float4*)(px);
        paE1 = *(const float4*)(px + 1024);
        pbE0 = *(const v8h*)(baseB + s * 32);
        pbE1 = *(const v8h*)(baseB + 32768 + s * 32);
    };
    auto loadO = [&](int s) {
        const float* px = baseX + (size_t)s * 32768;
        paO0 = *(const float4*)(px);
        paO1 = *(const float4*)(px + 1024);
        pbO0 = *(const v8h*)(baseB + s * 32);
        pbO1 = *(const v8h*)(baseB + 32768 + s * 32);
    };
    auto storeE = [&](int off) {
        uint_t* Asu = (uint_t*)(POOL + off);
        float a0[4] = {paE0.x, paE0.y, paE0.z, paE0.w};
        float a1[4] = {paE1.x, paE1.y, paE1.z, paE1.w};
        #pragma unroll
        for (int i = 0; i < 4; ++i) {
            int rm  = 4 * tq + i;
            int srm = i ^ (tq & 3);
            Asu[rm * 16 + ((cp >> 2) ^ srm) * 4 + (cp & 3)] =
                (uint_t)f2h(a0[i]) | ((uint_t)f2h(a1[i]) << 16);
        }
        _Float16* Bs = POOL + off + 2048;
        *(v8h*)&Bs[(r0 * 4 + (g ^ sr0)) * 8] = pbE0;
        *(v8h*)&Bs[((64 + r0) * 4 + (g ^ sr0)) * 8] = pbE1;   // s(64+r)==s(r)
    };
    auto storeO = [&](int off) {
        uint_t* Asu = (uint_t*)(POOL + off);
        float a0[4] = {paO0.x, paO0.y, paO0.z, paO0.w};
        float a1[4] = {paO1.x, paO1.y, paO1.z, paO1.w};
        #pragma unroll
        for (int i = 0; i < 4; ++i) {
            int rm  = 4 * tq + i;
            int srm = i ^ (tq & 3);
            Asu[rm * 16 + ((cp >> 2) ^ srm) * 4 + (cp & 3)] =
                (uint_t)f2h(a0[i]) | ((uint_t)f2h(a1[i]) << 16);
        }
        _Float16* Bs = POOL + off + 2048;
        *(v8h*)&Bs[(r0 * 4 + (g ^ sr0)) * 8] = pbO0;
        *(v8h*)&Bs[((64 + r0) * 4 + (g ^ sr0)) * 8] = pbO1;
    };

    v16f acc[2] = {{}, {}};            // [ns]: 32 tok x 2x32 d

    auto compute = [&](int off) {
        #pragma unroll
        for (int kc = 0; kc < 2; ++kc) {
            int rm  = wm * 32 + l31;
            int srm = (rm & 3) ^ ((rm >> 2) & 3);
            v8h af = *(const v8h*)&POOL[off + (rm * 4 + ((kc * 2 + h5) ^ srm)) * 8];
            v8h bf[2];
            #pragma unroll
            for (int ns = 0; ns < 2; ++ns) {
                int rn  = wn * 64 + ns * 32 + l31;
                int srn = (rn & 3) ^ ((rn >> 2) & 3);
                bf[ns] = *(const v8h*)&POOL[off + 2048 +
                           (rn * 4 + ((kc * 2 + h5) ^ srn)) * 8];
            }
            #pragma unroll
            for (int ns = 0; ns < 2; ++ns)
                acc[ns] = __builtin_amdgcn_mfma_f32_32x32x16_f16(
                    af, bf[ns], acc[ns], 0, 0, 0);
        }
    };

    // prologue: tile0 -> regsE -> LDS0; tile1 -> regsO (in flight)
    loadE(0);
    loadO(1);
    storeE(0);                 // waits only the 4 E-loads (vmcnt(4))
    __syncthreads();

    for (int sp = 0; sp < 8; ++sp) {
        const int s = 2 * sp;
        if (s < 14) loadE(s + 2);
        compute(0);
        storeO(6144);
        __syncthreads();
        if (s < 13) loadO(s + 3);
        compute(6144);
        if (s < 14) {
            storeE(0);
            __syncthreads();
        }
    }

    // ---- epilogue (all paths LDS-transpose then coalesced stores) ----
    __syncthreads();                 // staging LDS fully consumed
    if (which < 2) {
        ushort_t* oh = (which == 0) ? qf : kf;
        const float* bias = (which == 0) ? bq : bk;
        const int head = (nloc0 + wn * 64) >> 6;
        float bvv[2];
        bvv[0] = bias[nloc0 + wn * 64 + l31];
        bvv[1] = bias[nloc0 + wn * 64 + 32 + l31];
        // wave-private 4 KB: [32 tok][64 hd] halfs, 16B-granule XOR swizzle
        ushort_t* TWh = (ushort_t*)POOL + w * 2048;
        #pragma unroll
        for (int ns = 0; ns < 2; ++ns)
            #pragma unroll
            for (int r = 0; r < 16; ++r) {
                int tok = (r & 3) + 8 * (r >> 2) + 4 * h5;
                int hd  = ns * 32 + l31;
                int ch  = (hd >> 3) ^ (tok & 7);
                TWh[tok * 64 + ch * 8 + (hd & 7)] = f2h(acc[ns][r] + bvv[ns]);
            }
        __syncthreads();
        size_t baseg = (size_t)(b * HEADS_ + head) * 65536
                     + (size_t)(ntb + wm * 32) * 64;
        #pragma unroll
        for (int i = 0; i < 4; ++i) {
            int tok_r = i * 8 + (l >> 3);
            int ch_r  = l & 7;
            int ch_s  = ch_r ^ (tok_r & 7);
            uint4 v = *(uint4*)&TWh[tok_r * 64 + ch_s * 8];
            *(uint4*)&oh[baseg + (size_t)tok_r * 64 + ch_r * 8] = v;
        }
    } else {
        float bvv[2];
        #pragma unroll
        for (int ns = 0; ns < 2; ++ns)
            bvv[ns] = bv[nloc0 + wn * 64 + ns * 32 + l31];
        uint_t* TW = (uint_t*)POOL + w * 1024;   // wave-private 4 KB: [64 hd][16 w]
        #pragma unroll
        for (int ns = 0; ns < 2; ++ns)
            #pragma unroll
            for (int r = 0; r < 16; r += 2) {
                int tok_l = (r & 3) + 8 * (r >> 2) + 4 * h5;   // even
                int hd_l  = ns * 32 + l31;
                TW[hd_l * 16 + ((tok_l >> 1) ^ (hd_l & 15))] =
                    pkbf(acc[ns][r] + bvv[ns], acc[ns][r + 1] + bvv[ns]);
            }
        __syncthreads();
        const int head = (nloc0 + wn * 64) >> 6;
        uint_t* vtu = (uint_t*)vt;
        size_t base = (size_t)(b * HEADS_ + head) * 32768 + (size_t)l * 512
                    + (ntb + wm * 32) / 2;
        // kv-permutation baked into column order: swap bits 1<->2 of word idx
        // within each 8-word (16-token) block.
        #pragma unroll
        for (int c = 0; c < 4; ++c) {
            uint_t wd[4];
            #pragma unroll
            for (int kk = 0; kk < 4; ++kk) {
                int wsx = c * 4 + kk;
                int w3 = wsx & 7;
                int sw = (wsx & ~7) | (w3 & 1) | (((w3 >> 1) & 1) << 2)
                                   | (((w3 >> 2) & 1) << 1);
                wd[kk] = TW[l * 16 + (sw ^ (l & 15))];
            }
            *(uint4*)&vtu[base + c * 4] = *(uint4*)&wd[0];
        }
    }
}

// ---------------------------------------------------------------------------
// Kernel 2: MFMA flash attention, S^T form, fp16 QK^T + bf16 PV.
// Main loop = R5 (2-deep prefetch, double-buffered). NEW: out epilogue
// LDS-transposes per wave (aliasing the dead K/V tiles) so the final fp32
// stores are coalesced 128B row-segments (was: float4 per lane at 4KB
// lane-stride -> 64 txns per wave-store).
// ---------------------------------------------------------------------------
__global__ __launch_bounds__(256) void attn_kernel(
    const ushort_t* __restrict__ qf, const ushort_t* __restrict__ kf,
    const ushort_t* __restrict__ vt, float* __restrict__ out)
{
    __shared__ _Float16 POOL[16640];   // KH 16KB | VT 16KB | RS 512B
    _Float16* KH = POOL;
    ushort_t* VT = (ushort_t*)(POOL + 8192);
    float*    RS = (float*)(POOL + 16384);

    const int inst  = blockIdx.x;
    const int chunk = blockIdx.y;
    const int t     = threadIdx.x;
    const int w     = t >> 6;
    const int l     = t & 63;
    const int l31   = l & 31;
    const int h5    = l >> 5;

    const ushort_t* Qf = qf + (size_t)inst * 65536;
    const ushort_t* Kf = kf + (size_t)inst * 65536;
    const ushort_t* Vt = vt + (size_t)inst * 65536;

    const int qbase = chunk * 128 + w * 32;

    v8h aq[4];
    #pragma unroll
    for (int ks = 0; ks < 4; ++ks)
        aq[ks] = *(const v8h*)&Qf[(size_t)(qbase + l31) * 64 + ks * 16 + h5 * 8];

    const int g   = t & 7;
    const int r0  = t >> 3;            // 0..31, rep adds 32
    const int swz = g ^ (r0 & 7);
    const ushort_t* baseK = Kf + (size_t)r0 * 64 + g * 8;
    const ushort_t* baseV = Vt + (size_t)r0 * 1024 + g * 8;

    // two static-named prefetch sets
    v8h pkE0, pkE1, pkO0, pkO1;
    v8s pvE0, pvE1, pvO0, pvO1;

    auto loadE = [&](int kt) {
        pkE0 = *(const v8h*)(baseK + (size_t)kt * 4096);
        pkE1 = *(const v8h*)(baseK + (size_t)kt * 4096 + 2048);
        pvE0 = *(const v8s*)(baseV + (size_t)kt * 64);
        pvE1 = *(const v8s*)(baseV + 32768 + (size_t)kt * 64);
    };
    auto loadO = [&](int kt) {
        pkO0 = *(const v8h*)(baseK + (size_t)kt * 4096);
        pkO1 = *(const v8h*)(baseK + (size_t)kt * 4096 + 2048);
        pvO0 = *(const v8s*)(baseV + (size_t)kt * 64);
        pvO1 = *(const v8s*)(baseV + 32768 + (size_t)kt * 64);
    };
    auto storeE = [&](int off) {
        int so0 = (r0 * 8 + swz) * 8;
        int so1 = ((32 + r0) * 8 + swz) * 8;
        *(v8h*)&KH[off + so0] = pkE0;
        *(v8h*)&KH[off + so1] = pkE1;
        *(v8s*)&VT[off + so0] = pvE0;
        *(v8s*)&VT[off + so1] = pvE1;
    };
    auto storeO = [&](int off) {
        int so0 = (r0 * 8 + swz) * 8;
        int so1 = ((32 + r0) * 8 + swz) * 8;
        *(v8h*)&KH[off + so0] = pkO0;
        *(v8h*)&KH[off + so1] = pkO1;
        *(v8s*)&VT[off + so0] = pvO0;
        *(v8s*)&VT[off + so1] = pvO1;
    };

    v16f O0 = {}, O1 = {};
    float rsumv = 0.f;

    auto compute = [&](int off) {
        #pragma unroll
        for (int t2 = 0; t2 < 2; ++t2) {
            v16f s = {};
            int kvrow = t2 * 32 + l31;
            #pragma unroll
            for (int ks = 0; ks < 4; ++ks) {
                int so = (kvrow * 8 + ((ks * 2 + h5) ^ (kvrow & 7))) * 8;
                v8h khf = *(const v8h*)&KH[off + so];
                s = __builtin_amdgcn_mfma_f32_32x32x16_f16(khf, aq[ks], s, 0, 0, 0);
            }
            float e0[8], e1[8];
            #pragma unroll
            for (int j = 0; j < 8; ++j) {
                e0[j] = __expf(s[j] - 64.0f);
                e1[j] = __expf(s[8 + j] - 64.0f);
                rsumv += e0[j] + e1[j];
            }
            uint4 u0, u1;
            u0.x = pkbf(e0[0], e0[1]); u0.y = pkbf(e0[2], e0[3]);
            u0.z = pkbf(e0[4], e0[5]); u0.w = pkbf(e0[6], e0[7]);
            u1.x = pkbf(e1[0], e1[1]); u1.y = pkbf(e1[2], e1[3]);
            u1.z = pkbf(e1[4], e1[5]); u1.w = pkbf(e1[6], e1[7]);
            v8s p0 = __builtin_bit_cast(v8s, u0);
            v8s p1 = __builtin_bit_cast(v8s, u1);

            #pragma unroll
            for (int hh = 0; hh < 2; ++hh) {
                int rv = hh * 32 + l31;
                int g0 = (4 * t2 + h5)     ^ (rv & 7);
                int g1 = (4 * t2 + 2 + h5) ^ (rv & 7);
                v8s bv0 = *(const v8s*)&VT[off + (rv * 8 + g0) * 8];
                v8s bv1 = *(const v8s*)&VT[off + (rv * 8 + g1) * 8];
                if (hh == 0) {
                    O0 = __builtin_amdgcn_mfma_f32_32x32x16_bf16(p0, bv0, O0, 0, 0, 0);
                    O0 = __builtin_amdgcn_mfma_f32_32x32x16_bf16(p1, bv1, O0, 0, 0, 0);
                } else {
                    O1 = __builtin_amdgcn_mfma_f32_32x32x16_bf16(p0, bv0, O1, 0, 0, 0);
                    O1 = __builtin_amdgcn_mfma_f32_32x32x16_bf16(p1, bv1, O1, 0, 0, 0);
                }
            }
        }
    };

    // prologue
    loadE(0);
    loadO(1);
    storeE(0);
    __syncthreads();

    for (int sp = 0; sp < 8; ++sp) {
        const int kt = 2 * sp;
        if (kt < 14) loadE(kt + 2);
        compute(0);
        storeO(4096);
        __syncthreads();
        if (kt < 13) loadO(kt + 3);
        compute(4096);
        if (kt < 14) {
            storeE(0);
            __syncthreads();
        }
    }

    float tot = rsumv + __shfl_xor(rsumv, 32, 64);
    if (h5 == 0) RS[w * 32 + l31] = 1.0f / tot;
    __syncthreads();                  // also: all KH/VT reads retired
    float invr[16];
    #pragma unroll
    for (int r = 0; r < 16; ++r)
        invr[r] = RS[w * 32 + (r & 3) + 8 * (r >> 2) + 4 * h5];

    // ---- transpose O via wave-private 8 KB (aliases KH/VT) ----
    float* TWf = (float*)(POOL + w * 4096);       // [64 c][32 n] swizzled
    #pragma unroll
    for (int hh = 0; hh < 2; ++hh) {
        const v16f& O = hh ? O1 : O0;
        int c_loc = hh * 32 + l31;
        #pragma unroll
        for (int qd = 0; qd < 4; ++qd) {
            int gs = (2 * qd + h5) ^ (l31 & 7);   // c_loc&7 == l31&7
            float4 o4;
            o4.x = O[qd * 4 + 0] * invr[qd * 4 + 0];
            o4.y = O[qd * 4 + 1] * invr[qd * 4 + 1];
            o4.z = O[qd * 4 + 2] * invr[qd * 4 + 2];
            o4.w = O[qd * 4 + 3] * invr[qd * 4 + 3];
            *(float4*)&TWf[c_loc * 32 + gs * 4] = o4;
        }
    }
    __syncthreads();

    const int b    = inst >> 3;
    const int head = inst & 7;
    float* ob = out + (size_t)b * C_ * N_;
    #pragma unroll
    for (int i = 0; i < 8; ++i) {
        int c_r = i * 8 + (l >> 3);
        int gq  = l & 7;
        int gs  = gq ^ (c_r & 7);
        float4 v = *(const float4*)&TWf[c_r * 32 + gs * 4];
        *(float4*)&ob[(size_t)(head * 64 + c_r) * N_ + qbase + gq * 4] = v;
    }
}

// ---------------------------------------------------------------------------
extern "C" void kernel_launch(void* const* d_in, const int* in_sizes, int n_in,
                              void* d_out, int out_size, void* d_ws, size_t ws_size,
                              hipStream_t stream) {
    const float* x  = (const float*)d_in[0];
    const float* wq = (const float*)d_in[1];
    const float* bq = (const float*)d_in[2];
    const float* wk = (const float*)d_in[3];
    const float* bk = (const float*)d_in[4];
    const float* wv = (const float*)d_in[5];
    const float* bv = (const float*)d_in[6];
    float* out = (float*)d_out;

    char* ws = (char*)d_ws;                        // ~35 MiB used
    _Float16* wt = (_Float16*)(ws);                // 1536x512 fp16 = 1.5 MiB
    ushort_t* qf = (ushort_t*)(ws + 9961472);      // 8 MiB fp16
    ushort_t* kf = (ushort_t*)(ws + 18350080);     // 8 MiB fp16
    ushort_t* vt = (ushort_t*)(ws + 26738688);     // 8 MiB bf16

    prep_kernel<<<dim3(8, 8, 3), 256, 0, stream>>>(wq, wk, wv, (uint_t*)wt);
    proj_kernel<<<dim3(128, 12), 256, 0, stream>>>(x, wt, bq, bk, bv,
                                                   qf, kf, vt);
    attn_kernel<<<dim3(64, 8), 256, 0, stream>>>(qf, kf, vt, out);
}